// Round 12
// baseline (226.947 us; speedup 1.0000x reference)
//
#include <hip/hip_runtime.h>
#include <math.h>

// TensoIR physical rendering: N points x L lights -> 4 (N,3) outputs.
//
// R12: POINT-PAIR PACKED f32. Each wave handles TWO points, packed into the
// lo/hi halves of VOP3P packed-f32 registers (v_pk_fma_f32 & co, full-rate
// on CDNA). Why this packing axis (vs R9's light-pair, which was null):
//  - per-LIGHT table values are lane scalars broadcast to both halves ->
//    ZERO packing moves (R9 paid v_movs on every table value);
//  - per-point constants pack once in setup;
//  - stream reads stay dense per row (R11 lesson: wave must read rows
//    coalesced); p0/p1 are two dense rows;
//  - the 54-shuffle wave reduction + table reads + addressing now serve 2
//    points -> halved per-point.
// Est. VALU work 36us -> ~23us. Null ledger: R3/R5/R6/R8/R9/R10/R11.

#define PI_F     3.14159265358979323846f
#define FOURPI_F (4.0f * PI_F)
#define MAXL     512

typedef __attribute__((ext_vector_type(2))) float pf2;

__device__ __forceinline__ float fast_rcp(float x)  { float r; asm("v_rcp_f32 %0, %1" : "=v"(r) : "v"(x)); return r; }
__device__ __forceinline__ float fast_rsq(float x)  { float r; asm("v_rsq_f32 %0, %1" : "=v"(r) : "v"(x)); return r; }
__device__ __forceinline__ float fast_exp2(float x) { float r; asm("v_exp_f32 %0, %1" : "=v"(r) : "v"(x)); return r; }
__device__ __forceinline__ float fast_log2(float x) { float r; asm("v_log_f32 %0, %1" : "=v"(r) : "v"(x)); return r; }

__device__ __forceinline__ pf2 pk2(float a, float b) { pf2 r; r.x = a; r.y = b; return r; }
__device__ __forceinline__ pf2 pfma(pf2 a, pf2 b, pf2 c) { return __builtin_elementwise_fma(a, b, c); }
__device__ __forceinline__ pf2 pmin(pf2 a, pf2 b)        { return __builtin_elementwise_min(a, b); }
__device__ __forceinline__ pf2 pmax(pf2 a, pf2 b)        { return __builtin_elementwise_max(a, b); }
__device__ __forceinline__ pf2 prsq(pf2 x) { pf2 r; r.x = fast_rsq(x.x); r.y = fast_rsq(x.y); return r; }
__device__ __forceinline__ pf2 prcp(pf2 x) { pf2 r; r.x = fast_rcp(x.x); r.y = fast_rcp(x.y); return r; }
__device__ __forceinline__ pf2 pexp2(pf2 x){ pf2 r; r.x = fast_exp2(x.x); r.y = fast_exp2(x.y); return r; }

__device__ __forceinline__ float lin2srgb(float x) {
  float lin = 12.92f * x;
  float xe  = fmaxf(x, 1e-8f);
  float e   = 1.055f * fast_exp2(fast_log2(xe) * (1.0f / 2.4f)) - 0.055f;
  return (x <= 0.0031308f) ? lin : e;
}

__device__ __forceinline__ float clamp01(float x) { return fminf(fmaxf(x, 0.0f), 1.0f); }
__device__ __forceinline__ float clampe(float x)  { return fminf(fmaxf(x, 1e-6f), 1.0f); }

// ---------------- R12 point-pair packed kernel (L == 512) ----------------
__global__ void __launch_bounds__(256, 4)
tensoir_render_pp(const float* __restrict__ viewdirs,
                  const float* __restrict__ albedo,
                  const float* __restrict__ roughness,
                  const float* __restrict__ fresnel,
                  const float* __restrict__ normal,
                  const float* __restrict__ light_dirs,
                  const float* __restrict__ law,
                  const float* __restrict__ env_rgbs,
                  const float* __restrict__ visibility,  // (N,512)
                  const float* __restrict__ indirect,    // (N,512,3)
                  float* __restrict__ out, int N) {
  constexpr int L = 512;
  __shared__ float4 s_ld[MAXL];
  __shared__ float4 s_env[MAXL];

  const int tid  = threadIdx.x;
  const int lane = tid & 63;
  const int wid  = tid >> 6;

  // stage light table (per block)
  for (int l = tid; l < L; l += 256) {
    float lx = light_dirs[3 * l + 0];
    float ly = light_dirs[3 * l + 1];
    float lz = light_dirs[3 * l + 2];
    float inv = fast_rsq(fmaxf(lx * lx + ly * ly + lz * lz, 1e-12f));
    s_ld[l]  = make_float4(lx * inv, ly * inv, lz * inv, law[l]);
    s_env[l] = make_float4(env_rgbs[3 * l + 0], env_rgbs[3 * l + 1],
                           env_rgbs[3 * l + 2], 0.0f);
  }
  __syncthreads();

  // two consecutive points per wave
  int p0 = (blockIdx.x * 4 + wid) * 2;
  int p1 = p0 + 1;
  if (p0 >= N) p0 = N - 1;
  if (p1 >= N) p1 = N - 1;

  // ---- per-point setup, scalar, then packed ----
  pf2 nx2, ny2, nz2, vx2, vy2, vz2, sgn2, aNoV2;
  pf2 a2m1_2, onemk2, kk2, c1_2, alpha2_2;
  pf2 fr2, fg2, fb2, omfr2, omfg2, omfb2, ar2, ag2, ab2;
  {
    float sx[2][16];
    const int pp[2] = {p0, p1};
#pragma unroll
    for (int h = 0; h < 2; ++h) {
      const int n = pp[h];
      float vx = -viewdirs[3 * n + 0], vy = -viewdirs[3 * n + 1], vz = -viewdirs[3 * n + 2];
      float nx = normal[3 * n + 0], ny = normal[3 * n + 1], nz = normal[3 * n + 2];
      {
        float inv = fast_rsq(fmaxf(vx * vx + vy * vy + vz * vz, 1e-12f));
        vx *= inv; vy *= inv; vz *= inv;
      }
      {
        float inv = fast_rsq(fmaxf(nx * nx + ny * ny + nz * nz, 1e-12f));
        nx *= inv; ny *= inv; nz *= inv;
      }
      const float rough  = clamp01(roughness[n] * 0.9f + 0.09f);
      const float alpha  = rough * rough;
      const float alpha2 = alpha * alpha;
      const float kk     = (alpha + 2.0f * rough + 1.0f) * 0.125f;
      const float onemk  = 1.0f - kk;
      const float NoV0 = vx * nx + vy * ny + vz * nz;
      const float sgn  = (NoV0 >= 0.0f) ? 1.0f : -1.0f;
      const float aNoV = fabsf(NoV0);
      const float NoV  = clampe(aNoV);
      sx[h][0] = nx; sx[h][1] = ny; sx[h][2] = nz;
      sx[h][3] = vx; sx[h][4] = vy; sx[h][5] = vz;
      sx[h][6] = sgn; sx[h][7] = aNoV;
      sx[h][8] = alpha2 - 1.0f; sx[h][9] = onemk; sx[h][10] = kk;
      sx[h][11] = FOURPI_F * (NoV * onemk + kk);
      sx[h][12] = alpha2;
      sx[h][13] = clamp01(albedo[3 * n + 0]) * (1.0f / PI_F);
      sx[h][14] = clamp01(albedo[3 * n + 1]) * (1.0f / PI_F);
      sx[h][15] = clamp01(albedo[3 * n + 2]) * (1.0f / PI_F);
    }
    nx2 = pk2(sx[0][0], sx[1][0]); ny2 = pk2(sx[0][1], sx[1][1]); nz2 = pk2(sx[0][2], sx[1][2]);
    vx2 = pk2(sx[0][3], sx[1][3]); vy2 = pk2(sx[0][4], sx[1][4]); vz2 = pk2(sx[0][5], sx[1][5]);
    sgn2 = pk2(sx[0][6], sx[1][6]); aNoV2 = pk2(sx[0][7], sx[1][7]);
    a2m1_2 = pk2(sx[0][8], sx[1][8]); onemk2 = pk2(sx[0][9], sx[1][9]);
    kk2 = pk2(sx[0][10], sx[1][10]); c1_2 = pk2(sx[0][11], sx[1][11]);
    alpha2_2 = pk2(sx[0][12], sx[1][12]);
    ar2 = pk2(sx[0][13], sx[1][13]); ag2 = pk2(sx[0][14], sx[1][14]); ab2 = pk2(sx[0][15], sx[1][15]);
    fr2 = pk2(fresnel[3 * p0 + 0], fresnel[3 * p1 + 0]);
    fg2 = pk2(fresnel[3 * p0 + 1], fresnel[3 * p1 + 1]);
    fb2 = pk2(fresnel[3 * p0 + 2], fresnel[3 * p1 + 2]);
    omfr2 = 1.0f - fr2; omfg2 = 1.0f - fg2; omfb2 = 1.0f - fb2;
  }

  pf2 s1r = 0.0f, s1g = 0.0f, s1b = 0.0f;
  pf2 s2r = 0.0f, s2g = 0.0f, s2b = 0.0f;
  pf2 s3r = 0.0f, s3g = 0.0f, s3b = 0.0f;

  const float* vis0 = visibility + (size_t)p0 * L;
  const float* vis1 = visibility + (size_t)p1 * L;
  const float* ind0 = indirect + (size_t)p0 * L * 3;
  const float* ind1 = indirect + (size_t)p1 * L * 3;

#pragma unroll
  for (int j = 0; j < 8; ++j) {
    const int i = lane + 64 * j;
    const float4 ld = s_ld[i];     // lane scalars, broadcast to both halves
    const float4 ev = s_env[i];

    const pf2 vis2 = pk2(vis0[i], vis1[i]);
    const pf2 ir2  = pk2(ind0[3 * i + 0], ind1[3 * i + 0]);
    const pf2 ig2  = pk2(ind0[3 * i + 1], ind1[3 * i + 1]);
    const pf2 ib2  = pk2(ind0[3 * i + 2], ind1[3 * i + 2]);

    const pf2 cos0 = pfma(nz2, ld.z, pfma(ny2, ld.y, nx2 * ld.x));  // N.L per half
    const pf2 LoV  = pfma(vz2, ld.z, pfma(vy2, ld.y, vx2 * ld.x));  // V.L per half

    const pf2 w = pmax(cos0, 0.0f) * ld.w;

    const pf2 NoL0 = sgn2 * cos0;
    const pf2 NoL  = pmin(pmax(NoL0, 1e-6f), 1.0f);

    const pf2 h2   = pfma(LoV, 2.0f, 2.0f);
    const pf2 hinv = prsq(pmax(h2, 1e-12f));
    const pf2 VoH  = pmin(pmax((1.0f + LoV) * hinv, 1e-6f), 1.0f);
    const pf2 NoH  = pmin(pmax((NoL0 + aNoV2) * hinv, 1e-6f), 1.0f);

    const pf2 FMi = pfma(VoH, -5.55473f, -6.98316f) * VoH;
    const pf2 pw  = pexp2(FMi);
    const pf2 nom0 = pfma(NoH * NoH, a2m1_2, 1.0f);
    const pf2 nom2 = pfma(NoL, onemk2, kk2);
    const pf2 nom  = pmin(pmax(c1_2 * (nom0 * nom0) * nom2, 1e-6f), FOURPI_F);
    const pf2 ss   = alpha2_2 * prcp(nom);

    const pf2 br = pfma(pfma(omfr2, pw, fr2), ss, ar2);
    const pf2 bg = pfma(pfma(omfg2, pw, fg2), ss, ag2);
    const pf2 bb = pfma(pfma(omfb2, pw, fb2), ss, ab2);

    pf2 maskf;
    maskf.x = (cos0.x > 1e-6f) ? 1.0f : 0.0f;
    maskf.y = (cos0.y > 1e-6f) ? 1.0f : 0.0f;

    const pf2 twr = br * w, twg = bg * w, twb = bb * w;
    const pf2 tmr = twr * maskf, tmg = twg * maskf, tmb = twb * maskf;

    s1r = pfma(tmr, vis2 * ev.x, s1r);
    s1g = pfma(tmg, vis2 * ev.y, s1g);
    s1b = pfma(tmb, vis2 * ev.z, s1b);
    s2r = pfma(twr, ev.x, s2r);
    s2g = pfma(twg, ev.y, s2g);
    s2b = pfma(twb, ev.z, s2b);
    s3r = pfma(tmr, ir2, s3r);
    s3g = pfma(tmg, ig2, s3g);
    s3b = pfma(tmb, ib2, s3b);
  }

  // wave reduction: shuffle each half (2 shuffles per step per value)
#define WAVE_RED(v)                                              \
  do {                                                           \
    for (int m = 32; m >= 1; m >>= 1) {                          \
      pf2 o; o.x = __shfl_xor(v.x, m); o.y = __shfl_xor(v.y, m); \
      v += o;                                                    \
    }                                                            \
  } while (0)
  WAVE_RED(s1r); WAVE_RED(s1g); WAVE_RED(s1b);
  WAVE_RED(s2r); WAVE_RED(s2g); WAVE_RED(s2b);
  WAVE_RED(s3r); WAVE_RED(s3g); WAVE_RED(s3b);
#undef WAVE_RED

  if (lane == 0) {
    const size_t stride = (size_t)3 * N;
    // point p0 (lo halves)
    {
      float* o0 = out + 3 * (size_t)p0;
      float* o1 = o0 + stride;
      float* o2 = o1 + stride;
      float* o3 = o2 + stride;
      o0[0] = lin2srgb(clamp01(s1r.x + s3r.x));
      o0[1] = lin2srgb(clamp01(s1g.x + s3g.x));
      o0[2] = lin2srgb(clamp01(s1b.x + s3b.x));
      o1[0] = lin2srgb(s1r.x); o1[1] = lin2srgb(s1g.x); o1[2] = lin2srgb(s1b.x);
      o2[0] = lin2srgb(s2r.x); o2[1] = lin2srgb(s2g.x); o2[2] = lin2srgb(s2b.x);
      o3[0] = lin2srgb(s3r.x); o3[1] = lin2srgb(s3g.x); o3[2] = lin2srgb(s3b.x);
    }
    // point p1 (hi halves)
    {
      float* o0 = out + 3 * (size_t)p1;
      float* o1 = o0 + stride;
      float* o2 = o1 + stride;
      float* o3 = o2 + stride;
      o0[0] = lin2srgb(clamp01(s1r.y + s3r.y));
      o0[1] = lin2srgb(clamp01(s1g.y + s3g.y));
      o0[2] = lin2srgb(clamp01(s1b.y + s3b.y));
      o1[0] = lin2srgb(s1r.y); o1[1] = lin2srgb(s1g.y); o1[2] = lin2srgb(s1b.y);
      o2[0] = lin2srgb(s2r.y); o2[1] = lin2srgb(s2g.y); o2[2] = lin2srgb(s2b.y);
      o3[0] = lin2srgb(s3r.y); o3[1] = lin2srgb(s3g.y); o3[2] = lin2srgb(s3b.y);
    }
  }
}

// ---------------- fallback: R4 kernel (runtime L) ----------------
__global__ void __launch_bounds__(256)
tensoir_render_generic(const float* __restrict__ viewdirs,
                       const float* __restrict__ albedo,
                       const float* __restrict__ roughness,
                       const float* __restrict__ fresnel,
                       const float* __restrict__ normal,
                       const float* __restrict__ light_dirs,
                       const float* __restrict__ law,
                       const float* __restrict__ env_rgbs,
                       const float* __restrict__ visibility,
                       const float* __restrict__ indirect,
                       float* __restrict__ out, int N, int L) {
  __shared__ float4 s_ld[MAXL];
  __shared__ float4 s_env[MAXL];

  const int tid = threadIdx.x;
  const int lane = tid & 63;
  int n = blockIdx.x * 4 + (tid >> 6);
  if (n >= N) n = N - 1;

  float vx = -viewdirs[3 * n + 0], vy = -viewdirs[3 * n + 1], vz = -viewdirs[3 * n + 2];
  float nx = normal[3 * n + 0], ny = normal[3 * n + 1], nz = normal[3 * n + 2];
  float rough0 = roughness[n];
  const float fr = fresnel[3 * n + 0], fg = fresnel[3 * n + 1], fb = fresnel[3 * n + 2];
  float ar0 = albedo[3 * n + 0], ag0 = albedo[3 * n + 1], ab0 = albedo[3 * n + 2];

  for (int l = tid; l < L && l < MAXL; l += 256) {
    float lx = light_dirs[3 * l + 0];
    float ly = light_dirs[3 * l + 1];
    float lz = light_dirs[3 * l + 2];
    float inv = fast_rsq(fmaxf(lx * lx + ly * ly + lz * lz, 1e-12f));
    s_ld[l]  = make_float4(lx * inv, ly * inv, lz * inv, law[l]);
    s_env[l] = make_float4(env_rgbs[3 * l + 0], env_rgbs[3 * l + 1],
                           env_rgbs[3 * l + 2], 0.0f);
  }
  __syncthreads();

  {
    float inv = fast_rsq(fmaxf(vx * vx + vy * vy + vz * vz, 1e-12f));
    vx *= inv; vy *= inv; vz *= inv;
  }
  {
    float inv = fast_rsq(fmaxf(nx * nx + ny * ny + nz * nz, 1e-12f));
    nx *= inv; ny *= inv; nz *= inv;
  }
  const float rough  = clamp01(rough0 * 0.9f + 0.09f);
  const float alpha  = rough * rough;
  const float alpha2 = alpha * alpha;
  const float a2m1   = alpha2 - 1.0f;
  const float kk     = (alpha + 2.0f * rough + 1.0f) * 0.125f;
  const float onemk  = 1.0f - kk;
  const float omfr = 1.0f - fr, omfg = 1.0f - fg, omfb = 1.0f - fb;
  const float ar = clamp01(ar0) * (1.0f / PI_F);
  const float ag = clamp01(ag0) * (1.0f / PI_F);
  const float ab = clamp01(ab0) * (1.0f / PI_F);
  const float NoV0 = vx * nx + vy * ny + vz * nz;
  const float sgn  = (NoV0 >= 0.0f) ? 1.0f : -1.0f;
  const float aNoV = fabsf(NoV0);
  const float NoV  = clampe(aNoV);
  const float nom1 = NoV * onemk + kk;
  const float c1   = FOURPI_F * nom1;

  float s1r = 0, s1g = 0, s1b = 0;
  float s2r = 0, s2g = 0, s2b = 0;
  float s3r = 0, s3g = 0, s3b = 0;

  const float* visrow = visibility + (size_t)n * L;
  const float* indrow = indirect + (size_t)n * L * 3;

  for (int i = lane; i < L; i += 64) {
    const float4 ld = s_ld[i];
    const float4 ev = s_env[i];
    const float visv = visrow[i];
    const float ir = indrow[3 * i + 0];
    const float ig = indrow[3 * i + 1];
    const float ib = indrow[3 * i + 2];
    const float cos0 = ld.x * nx + ld.y * ny + ld.z * nz;
    const float LoV  = ld.x * vx + ld.y * vy + ld.z * vz;
    const float cosine = fmaxf(cos0, 0.0f);
    const bool  mask   = cos0 > 1e-6f;
    const float w      = cosine * ld.w;
    const float NoL0 = sgn * cos0;
    const float NoL  = clampe(NoL0);
    const float h2   = fmaf(2.0f, LoV, 2.0f);
    const float hinv = fast_rsq(fmaxf(h2, 1e-12f));
    const float VoH  = clampe((1.0f + LoV) * hinv);
    const float NoH  = clampe((NoL0 + aNoV) * hinv);
    const float FMi = (-5.55473f * VoH - 6.98316f) * VoH;
    const float p2  = fast_exp2(FMi);
    const float nom0 = fmaf(NoH * NoH, a2m1, 1.0f);
    const float nom2 = fmaf(NoL, onemk, kk);
    const float nom  = fminf(fmaxf(c1 * (nom0 * nom0) * nom2, 1e-6f), FOURPI_F);
    const float ss   = alpha2 * fast_rcp(nom);
    const float br = fmaf(fmaf(omfr, p2, fr), ss, ar);
    const float bg = fmaf(fmaf(omfg, p2, fg), ss, ag);
    const float bb = fmaf(fmaf(omfb, p2, fb), ss, ab);
    const float vism = mask ? visv : 0.0f;
    const float irm  = mask ? ir : 0.0f;
    const float igm  = mask ? ig : 0.0f;
    const float ibm  = mask ? ib : 0.0f;
    const float twr = br * w, twg = bg * w, twb = bb * w;
    s1r = fmaf(twr, vism * ev.x, s1r);
    s1g = fmaf(twg, vism * ev.y, s1g);
    s1b = fmaf(twb, vism * ev.z, s1b);
    s2r = fmaf(twr, ev.x, s2r);
    s2g = fmaf(twg, ev.y, s2g);
    s2b = fmaf(twb, ev.z, s2b);
    s3r = fmaf(twr, irm, s3r);
    s3g = fmaf(twg, igm, s3g);
    s3b = fmaf(twb, ibm, s3b);
  }

#define WAVE_RED(v)                 \
  do {                              \
    v += __shfl_xor(v, 32);         \
    v += __shfl_xor(v, 16);         \
    v += __shfl_xor(v, 8);          \
    v += __shfl_xor(v, 4);          \
    v += __shfl_xor(v, 2);          \
    v += __shfl_xor(v, 1);          \
  } while (0)
  WAVE_RED(s1r); WAVE_RED(s1g); WAVE_RED(s1b);
  WAVE_RED(s2r); WAVE_RED(s2g); WAVE_RED(s2b);
  WAVE_RED(s3r); WAVE_RED(s3g); WAVE_RED(s3b);
#undef WAVE_RED

  if (lane == 0) {
    const size_t stride = (size_t)3 * N;
    float* o0 = out + 3 * (size_t)n;
    float* o1 = o0 + stride;
    float* o2 = o1 + stride;
    float* o3 = o2 + stride;
    o0[0] = lin2srgb(clamp01(s1r + s3r));
    o0[1] = lin2srgb(clamp01(s1g + s3g));
    o0[2] = lin2srgb(clamp01(s1b + s3b));
    o1[0] = lin2srgb(s1r); o1[1] = lin2srgb(s1g); o1[2] = lin2srgb(s1b);
    o2[0] = lin2srgb(s2r); o2[1] = lin2srgb(s2g); o2[2] = lin2srgb(s2b);
    o3[0] = lin2srgb(s3r); o3[1] = lin2srgb(s3g); o3[2] = lin2srgb(s3b);
  }
}

extern "C" void kernel_launch(void* const* d_in, const int* in_sizes, int n_in,
                              void* d_out, int out_size, void* d_ws, size_t ws_size,
                              hipStream_t stream) {
  const float* viewdirs   = (const float*)d_in[0];
  const float* albedo     = (const float*)d_in[1];
  const float* roughness  = (const float*)d_in[2];
  const float* fresnel    = (const float*)d_in[3];
  const float* normal     = (const float*)d_in[4];
  const float* light_dirs = (const float*)d_in[5];
  const float* law        = (const float*)d_in[6];
  const float* env_rgbs   = (const float*)d_in[7];
  const float* visibility = (const float*)d_in[8];
  const float* indirect   = (const float*)d_in[9];
  float* out = (float*)d_out;

  const int N = in_sizes[0] / 3;
  const int L = in_sizes[6];   // light_area_weight is (L,)

  dim3 block(256);

  if (L == 512) {
    const int blocks = (N + 7) / 8;   // 8 points per block (2 per wave)
    hipLaunchKernelGGL(tensoir_render_pp, dim3(blocks), block, 0, stream,
                       viewdirs, albedo, roughness, fresnel, normal,
                       light_dirs, law, env_rgbs, visibility, indirect,
                       out, N);
  } else {
    const int blocks = (N + 3) / 4;
    hipLaunchKernelGGL(tensoir_render_generic, dim3(blocks), block, 0, stream,
                       viewdirs, albedo, roughness, fresnel, normal,
                       light_dirs, law, env_rgbs, visibility, indirect,
                       out, N, L);
  }
}